// Round 7
// baseline (827.617 us; speedup 1.0000x reference)
//
#include <hip/hip_runtime.h>
#include <math.h>

#define NN 50000
#define NE 1600000
#define NBIN 391    // ceil(NN/128)
#define BINW 128    // nodes per bin
#define STCAP 6144  // staged edges per bin (mean 4092, +4sigma ~4350)
#define OVFCAP 32768

// ---- bf16 helpers (bit-level, RNE pack) ----
__device__ __forceinline__ float blo(unsigned u) { return __uint_as_float(u << 16); }
__device__ __forceinline__ float bhi(unsigned u) { return __uint_as_float(u & 0xffff0000u); }
__device__ __forceinline__ unsigned bpack(float a, float b) {
    unsigned ua = __float_as_uint(a), ub = __float_as_uint(b);
    ua += 0x7fffu + ((ua >> 16) & 1u);
    ub += 0x7fffu + ((ub >> 16) & 1u);
    return (ua >> 16) | (ub & 0xffff0000u);
}

// edge_index may arrive as int64 (reference dtype) or int32 (harness-normalized).
__device__ __forceinline__ int edge_get(const void* ei, int is64, long long i) {
    return is64 ? (int)((const long long*)ei)[i] : ((const int*)ei)[i];
}

__global__ void k_detect(const unsigned int* __restrict__ e, int* flag) {
    unsigned int v = e[2 * threadIdx.x + 1];
    unsigned long long m = __ballot(v != 0u);
    if (threadIdx.x == 0) *flag = (m == 0ull) ? 1 : 0;
}

// ---- Pass 1: bin edges by dst>>7 into per-bin staged regions (packed (d<<16)|s) ----
__global__ __launch_bounds__(256) void k_bin(const void* __restrict__ ei,
                                             const int* __restrict__ flag,
                                             int* __restrict__ bincnt,
                                             unsigned* __restrict__ staged,
                                             int* __restrict__ ovfcnt,
                                             unsigned* __restrict__ ovf) {
    int is64 = *flag;
    for (long long e = (long long)blockIdx.x * 256 + threadIdx.x; e < NE;
         e += (long long)gridDim.x * 256) {
        int s = edge_get(ei, is64, e);
        int d = edge_get(ei, is64, (long long)NE + e);
        unsigned p = ((unsigned)d << 16) | (unsigned)s;
        int bin = d >> 7;
        int pos = atomicAdd(&bincnt[bin], 1);
        if (pos < STCAP) {
            staged[(long long)bin * STCAP + pos] = p;
        } else {
            int o = atomicAdd(ovfcnt, 1);
            if (o < OVFCAP) ovf[o] = p;
        }
    }
}

// ---- exclusive scan of bincnt -> binbase (csr index space); one block ----
__global__ __launch_bounds__(512) void k_binscan(const int* __restrict__ bincnt,
                                                 int* __restrict__ binbase) {
    __shared__ int s[512];
    int t = threadIdx.x;
    int v = (t < NBIN) ? bincnt[t] : 0;
    s[t] = v;
    __syncthreads();
#pragma unroll
    for (int off = 1; off < 512; off <<= 1) {
        int u = (t >= off) ? s[t - off] : 0;
        __syncthreads();
        s[t] += u;
        __syncthreads();
    }
    if (t < NBIN) binbase[t] = s[t] - v;
}

// ---- Pass 2: per bin, LDS count + scan; write rowstart/cnt/dinv; scatter csr ----
__global__ __launch_bounds__(256) void k_csr(const unsigned* __restrict__ staged,
                                             const int* __restrict__ bincnt,
                                             const int* __restrict__ binbase,
                                             const int* __restrict__ ovfcnt,
                                             const unsigned* __restrict__ ovf,
                                             int* __restrict__ rowstart,
                                             int* __restrict__ cnt,
                                             float* __restrict__ dinv,
                                             int* __restrict__ csr) {
    __shared__ int lcnt[BINW], lpre[BINW], lcur[BINW];
    int b = blockIdx.x, t = threadIdx.x;
    int n = min(bincnt[b], STCAP);
    int novf = *ovfcnt;  // statistically 0
    const unsigned* st = staged + (long long)b * STCAP;
    if (t < BINW) { lcnt[t] = 0; lcur[t] = 0; }
    __syncthreads();
    for (int j = t; j < n; j += 256) atomicAdd(&lcnt[(st[j] >> 16) & (BINW - 1)], 1);
    for (int j = t; j < novf; j += 256) {
        unsigned p = ovf[j];
        if ((int)(p >> 23) == b) atomicAdd(&lcnt[(p >> 16) & (BINW - 1)], 1);
    }
    __syncthreads();
    if (t < BINW) lpre[t] = lcnt[t];
    __syncthreads();
#pragma unroll
    for (int off = 1; off < BINW; off <<= 1) {
        int u = (t < BINW && t >= off) ? lpre[t - off] : 0;
        __syncthreads();
        if (t < BINW && t >= off) lpre[t] += u;
        __syncthreads();
    }
    int base = binbase[b];
    if (t < BINW) {
        int c = lcnt[t];
        int ex = lpre[t] - c;  // exclusive prefix
        lpre[t] = ex;
        int node = b * BINW + t;
        if (node < NN) {
            rowstart[node] = base + ex;
            cnt[node] = c;
            dinv[node] = rsqrtf((float)c + 1.0f);
        }
    }
    __syncthreads();
    for (int j = t; j < n; j += 256) {
        unsigned p = st[j];
        int dloc = (p >> 16) & (BINW - 1);
        int pos = base + lpre[dloc] + atomicAdd(&lcur[dloc], 1);
        csr[pos] = (int)(p & 0xffffu);
    }
    for (int j = t; j < novf; j += 256) {
        unsigned p = ovf[j];
        if ((int)(p >> 23) == b) {
            int dloc = (p >> 16) & (BINW - 1);
            int pos = base + lpre[dloc] + atomicAdd(&lcur[dloc], 1);
            csr[pos] = (int)(p & 0xffffu);
        }
    }
}

// ---- GEMM with dinv-row-scale epilogue, bf16 output.
// BM=64 rows, full CN cols, 256 threads (16x16), per-thread 4 rows x (CN/64 groups of 4 cols).
template <int K, int CN, bool XBF>
__global__ __launch_bounds__(256) void k_gemm_scale(const void* __restrict__ Xv,
                                                    const float* __restrict__ W,
                                                    const float* __restrict__ dinv,
                                                    unsigned int* __restrict__ outb) {
    const int BM = 64, KT = 16, G = CN / 64;
    __shared__ float As[KT][BM + 4];
    __shared__ float Bs[KT][CN];
    int tid = threadIdx.x;
    int tx = tid & 15, ty = tid >> 4;
    int row0 = blockIdx.x * BM;
    float acc[4][G * 4];
#pragma unroll
    for (int a = 0; a < 4; a++)
#pragma unroll
        for (int b = 0; b < G * 4; b++) acc[a][b] = 0.f;

    for (int k0 = 0; k0 < K; k0 += KT) {
        if (XBF) {
            if (tid < 128) {
                int r = tid >> 1, kc = tid & 1, rr = row0 + r;
                uint4 v = {0, 0, 0, 0};
                if (rr < NN)
                    v = ((const uint4*)Xv)[((long long)rr * K + k0 + 8 * kc) >> 3];
                int kb = 8 * kc;
                As[kb + 0][r] = blo(v.x); As[kb + 1][r] = bhi(v.x);
                As[kb + 2][r] = blo(v.y); As[kb + 3][r] = bhi(v.y);
                As[kb + 4][r] = blo(v.z); As[kb + 5][r] = bhi(v.z);
                As[kb + 6][r] = blo(v.w); As[kb + 7][r] = bhi(v.w);
            }
        } else {
            int r = tid >> 2, kc = tid & 3, rr = row0 + r;
            float4 v = {0.f, 0.f, 0.f, 0.f};
            if (rr < NN)
                v = *(const float4*)((const float*)Xv + (long long)rr * K + k0 + 4 * kc);
            int kb = 4 * kc;
            As[kb + 0][r] = v.x; As[kb + 1][r] = v.y;
            As[kb + 2][r] = v.z; As[kb + 3][r] = v.w;
        }
#pragma unroll
        for (int j = 0; j < (KT * CN / 4) / 256; j++) {
            int q = tid + 256 * j;
            int kk = q / (CN / 4), c4 = q % (CN / 4);
            *(float4*)&Bs[kk][4 * c4] = *(const float4*)&W[(long long)(k0 + kk) * CN + 4 * c4];
        }
        __syncthreads();
#pragma unroll
        for (int kk = 0; kk < KT; kk++) {
            float4 av = *(const float4*)&As[kk][ty * 4];
            float am[4] = {av.x, av.y, av.z, av.w};
            float bm[G][4];
#pragma unroll
            for (int g = 0; g < G; g++) {
                float4 bv = *(const float4*)&Bs[kk][g * 64 + tx * 4];
                bm[g][0] = bv.x; bm[g][1] = bv.y; bm[g][2] = bv.z; bm[g][3] = bv.w;
            }
#pragma unroll
            for (int mi = 0; mi < 4; mi++)
#pragma unroll
                for (int g = 0; g < G; g++)
#pragma unroll
                    for (int ni = 0; ni < 4; ni++)
                        acc[mi][g * 4 + ni] = fmaf(am[mi], bm[g][ni], acc[mi][g * 4 + ni]);
        }
        __syncthreads();
    }
#pragma unroll
    for (int mi = 0; mi < 4; mi++) {
        int r = row0 + ty * 4 + mi;
        if (r < NN) {
            float s = dinv[r];
#pragma unroll
            for (int g = 0; g < G; g++) {
                uint2 u;
                u.x = bpack(s * acc[mi][g * 4 + 0], s * acc[mi][g * 4 + 1]);
                u.y = bpack(s * acc[mi][g * 4 + 2], s * acc[mi][g * 4 + 3]);
                long long elem = (long long)r * CN + g * 64 + tx * 4;
                *(uint2*)(outb + (elem >> 1)) = u;
            }
        }
    }
}

// ---- Layer-1 aggregate: out1 = relu(dinv*(self + sum_in h1) + b). bf16 in/out.
// 16 lanes/node (8 ch each), 16 nodes/block.
__global__ __launch_bounds__(256) void k_gather_relu(const uint4* __restrict__ h,
                                                     const int* __restrict__ csr,
                                                     const int* __restrict__ rowstart,
                                                     const int* __restrict__ cnt,
                                                     const float* __restrict__ dinv,
                                                     const float* __restrict__ bias,
                                                     uint4* __restrict__ out) {
    int tid = threadIdx.x;
    int node = blockIdx.x * 16 + (tid >> 4);
    int cl = tid & 15;
    if (node >= NN) return;
    int beg = rowstart[node], n = cnt[node];
    float acc[8];
    {
        uint4 v = h[(long long)node * 16 + cl];
        acc[0] = blo(v.x); acc[1] = bhi(v.x); acc[2] = blo(v.y); acc[3] = bhi(v.y);
        acc[4] = blo(v.z); acc[5] = bhi(v.z); acc[6] = blo(v.w); acc[7] = bhi(v.w);
    }
    int j = 0;
    for (; j + 3 < n; j += 4) {
        int a0 = csr[beg + j], a1 = csr[beg + j + 1];
        int a2 = csr[beg + j + 2], a3 = csr[beg + j + 3];
        uint4 v0 = h[(long long)a0 * 16 + cl], v1 = h[(long long)a1 * 16 + cl];
        uint4 v2 = h[(long long)a2 * 16 + cl], v3 = h[(long long)a3 * 16 + cl];
        acc[0] += blo(v0.x); acc[1] += bhi(v0.x); acc[2] += blo(v0.y); acc[3] += bhi(v0.y);
        acc[4] += blo(v0.z); acc[5] += bhi(v0.z); acc[6] += blo(v0.w); acc[7] += bhi(v0.w);
        acc[0] += blo(v1.x); acc[1] += bhi(v1.x); acc[2] += blo(v1.y); acc[3] += bhi(v1.y);
        acc[4] += blo(v1.z); acc[5] += bhi(v1.z); acc[6] += blo(v1.w); acc[7] += bhi(v1.w);
        acc[0] += blo(v2.x); acc[1] += bhi(v2.x); acc[2] += blo(v2.y); acc[3] += bhi(v2.y);
        acc[4] += blo(v2.z); acc[5] += bhi(v2.z); acc[6] += blo(v2.w); acc[7] += bhi(v2.w);
        acc[0] += blo(v3.x); acc[1] += bhi(v3.x); acc[2] += blo(v3.y); acc[3] += bhi(v3.y);
        acc[4] += blo(v3.z); acc[5] += bhi(v3.z); acc[6] += blo(v3.w); acc[7] += bhi(v3.w);
    }
    for (; j < n; j++) {
        uint4 v = h[(long long)csr[beg + j] * 16 + cl];
        acc[0] += blo(v.x); acc[1] += bhi(v.x); acc[2] += blo(v.y); acc[3] += bhi(v.y);
        acc[4] += blo(v.z); acc[5] += bhi(v.z); acc[6] += blo(v.w); acc[7] += bhi(v.w);
    }
    float d = dinv[node];
    float4 b0 = *(const float4*)&bias[cl * 8];
    float4 b1 = *(const float4*)&bias[cl * 8 + 4];
    float r0 = fmaxf(fmaf(d, acc[0], b0.x), 0.f), r1 = fmaxf(fmaf(d, acc[1], b0.y), 0.f);
    float r2 = fmaxf(fmaf(d, acc[2], b0.z), 0.f), r3 = fmaxf(fmaf(d, acc[3], b0.w), 0.f);
    float r4 = fmaxf(fmaf(d, acc[4], b1.x), 0.f), r5 = fmaxf(fmaf(d, acc[5], b1.y), 0.f);
    float r6 = fmaxf(fmaf(d, acc[6], b1.z), 0.f), r7 = fmaxf(fmaf(d, acc[7], b1.w), 0.f);
    uint4 o;
    o.x = bpack(r0, r1); o.y = bpack(r2, r3); o.z = bpack(r4, r5); o.w = bpack(r6, r7);
    out[(long long)node * 16 + cl] = o;
}

// ---- Layer-2 aggregate + bias + log_softmax. bf16 in, f32 out.
// 8 lanes/node (8 ch each), 32 nodes/block; shfl_xor reduce within 8-lane group.
__global__ __launch_bounds__(256) void k_gather_lsm(const uint4* __restrict__ h,
                                                    const int* __restrict__ csr,
                                                    const int* __restrict__ rowstart,
                                                    const int* __restrict__ cnt,
                                                    const float* __restrict__ dinv,
                                                    const float* __restrict__ bias,
                                                    float* __restrict__ out) {
    int tid = threadIdx.x;
    int node = blockIdx.x * 32 + (tid >> 3);
    int cl = tid & 7;
    if (node >= NN) return;
    int beg = rowstart[node], n = cnt[node];
    float acc[8];
    {
        uint4 v = h[(long long)node * 8 + cl];
        acc[0] = blo(v.x); acc[1] = bhi(v.x); acc[2] = blo(v.y); acc[3] = bhi(v.y);
        acc[4] = blo(v.z); acc[5] = bhi(v.z); acc[6] = blo(v.w); acc[7] = bhi(v.w);
    }
    int j = 0;
    for (; j + 3 < n; j += 4) {
        int a0 = csr[beg + j], a1 = csr[beg + j + 1];
        int a2 = csr[beg + j + 2], a3 = csr[beg + j + 3];
        uint4 v0 = h[(long long)a0 * 8 + cl], v1 = h[(long long)a1 * 8 + cl];
        uint4 v2 = h[(long long)a2 * 8 + cl], v3 = h[(long long)a3 * 8 + cl];
        acc[0] += blo(v0.x); acc[1] += bhi(v0.x); acc[2] += blo(v0.y); acc[3] += bhi(v0.y);
        acc[4] += blo(v0.z); acc[5] += bhi(v0.z); acc[6] += blo(v0.w); acc[7] += bhi(v0.w);
        acc[0] += blo(v1.x); acc[1] += bhi(v1.x); acc[2] += blo(v1.y); acc[3] += bhi(v1.y);
        acc[4] += blo(v1.z); acc[5] += bhi(v1.z); acc[6] += blo(v1.w); acc[7] += bhi(v1.w);
        acc[0] += blo(v2.x); acc[1] += bhi(v2.x); acc[2] += blo(v2.y); acc[3] += bhi(v2.y);
        acc[4] += blo(v2.z); acc[5] += bhi(v2.z); acc[6] += blo(v2.w); acc[7] += bhi(v2.w);
        acc[0] += blo(v3.x); acc[1] += bhi(v3.x); acc[2] += blo(v3.y); acc[3] += bhi(v3.y);
        acc[4] += blo(v3.z); acc[5] += bhi(v3.z); acc[6] += blo(v3.w); acc[7] += bhi(v3.w);
    }
    for (; j < n; j++) {
        uint4 v = h[(long long)csr[beg + j] * 8 + cl];
        acc[0] += blo(v.x); acc[1] += bhi(v.x); acc[2] += blo(v.y); acc[3] += bhi(v.y);
        acc[4] += blo(v.z); acc[5] += bhi(v.z); acc[6] += blo(v.w); acc[7] += bhi(v.w);
    }
    float d = dinv[node];
    float4 b0 = *(const float4*)&bias[cl * 8];
    float4 b1 = *(const float4*)&bias[cl * 8 + 4];
    float t[8];
    t[0] = fmaf(d, acc[0], b0.x); t[1] = fmaf(d, acc[1], b0.y);
    t[2] = fmaf(d, acc[2], b0.z); t[3] = fmaf(d, acc[3], b0.w);
    t[4] = fmaf(d, acc[4], b1.x); t[5] = fmaf(d, acc[5], b1.y);
    t[6] = fmaf(d, acc[6], b1.z); t[7] = fmaf(d, acc[7], b1.w);
    float m = t[0];
#pragma unroll
    for (int i = 1; i < 8; i++) m = fmaxf(m, t[i]);
#pragma unroll
    for (int o = 1; o < 8; o <<= 1) m = fmaxf(m, __shfl_xor(m, o));
    float ex = 0.f;
#pragma unroll
    for (int i = 0; i < 8; i++) ex += __expf(t[i] - m);
#pragma unroll
    for (int o = 1; o < 8; o <<= 1) ex += __shfl_xor(ex, o);
    float l = logf(ex);
    float4 w0 = {t[0] - m - l, t[1] - m - l, t[2] - m - l, t[3] - m - l};
    float4 w1 = {t[4] - m - l, t[5] - m - l, t[6] - m - l, t[7] - m - l};
    *(float4*)&out[(long long)node * 64 + cl * 8] = w0;
    *(float4*)&out[(long long)node * 64 + cl * 8 + 4] = w1;
}

extern "C" void kernel_launch(void* const* d_in, const int* in_sizes, int n_in,
                              void* d_out, int out_size, void* d_ws, size_t ws_size,
                              hipStream_t stream) {
    const float* x  = (const float*)d_in[0];
    const void*  ei = d_in[1];
    const float* W1 = (const float*)d_in[2];
    const float* b1 = (const float*)d_in[3];
    const float* W2 = (const float*)d_in[4];
    const float* b2 = (const float*)d_in[5];
    float* out = (float*)d_out;

    char* ws = (char*)d_ws;
    float*    dinv     = (float*)   (ws + 0x000000);  // 200 KB
    int*      flag     = (int*)     (ws + 0x040000);
    int*      cnt      = (int*)     (ws + 0x050000);  // 200 KB
    int*      rowstart = (int*)     (ws + 0x090000);  // 200 KB
    int*      bincnt   = (int*)     (ws + 0x0D0000);  // NBIN ints (+ ovfcnt right after)
    int*      ovfcnt   = (int*)     (ws + 0x0D0000 + NBIN * 4);
    int*      binbase  = (int*)     (ws + 0x0D2000);  // NBIN ints
    unsigned* ovf      = (unsigned*)(ws + 0x0E0000);  // 128 KB
    int*      csr      = (int*)     (ws + 0x120000);  // 6.4 MB
    unsigned* h1       = (unsigned*)(ws + 0x740000);  // bf16 12.8 MB (h1, then h2)
    unsigned* out1     = (unsigned*)(ws + 0x1400000); // bf16 12.8 MB
    unsigned* staged   = (unsigned*)(ws + 0x1400000); // 9.6 MB, aliases out1 (dead before gemm1)

    k_detect<<<1, 64, 0, stream>>>((const unsigned int*)ei, flag);
    hipMemsetAsync(bincnt, 0, (size_t)(NBIN + 1) * 4, stream);  // bincnt + ovfcnt
    k_bin<<<2048, 256, 0, stream>>>(ei, flag, bincnt, staged, ovfcnt, ovf);
    k_binscan<<<1, 512, 0, stream>>>(bincnt, binbase);
    k_csr<<<NBIN, 256, 0, stream>>>(staged, bincnt, binbase, ovfcnt, ovf,
                                    rowstart, cnt, dinv, csr);

    // Layer 1: h1 = bf16(dinv .* (x@W1)); out1 = bf16(relu(dinv.*(agg+self) + b1))
    k_gemm_scale<256, 128, false><<<(NN + 63) / 64, 256, 0, stream>>>(x, W1, dinv, h1);
    k_gather_relu<<<(NN + 15) / 16, 256, 0, stream>>>((const uint4*)h1, csr, rowstart, cnt,
                                                      dinv, b1, (uint4*)out1);

    // Layer 2: h2 = bf16(dinv .* (out1@W2)); out = log_softmax(dinv.*(agg+self) + b2)
    k_gemm_scale<128, 64, true><<<(NN + 63) / 64, 256, 0, stream>>>(out1, W2, dinv, h1);
    k_gather_lsm<<<(NN + 31) / 32, 256, 0, stream>>>((const uint4*)h1, csr, rowstart, cnt,
                                                     dinv, b2, out);
}

// Round 9
// 293.339 us; speedup vs baseline: 2.8214x; 2.8214x over previous
//
#include <hip/hip_runtime.h>
#include <math.h>

#define NN 50000
#define NE 1600000
#define NBIN 391    // ceil(NN/128)
#define BINW 128    // nodes per bin
#define STCAP 6144  // staged edges per bin (mean 4092)
#define OVFCAP 32768
#define NBLK 512
#define EPB 3125    // NE / NBLK exactly

// ---- bf16 helpers (bit-level, RNE pack) ----
__device__ __forceinline__ float blo(unsigned u) { return __uint_as_float(u << 16); }
__device__ __forceinline__ float bhi(unsigned u) { return __uint_as_float(u & 0xffff0000u); }
__device__ __forceinline__ unsigned bpack(float a, float b) {
    unsigned ua = __float_as_uint(a), ub = __float_as_uint(b);
    ua += 0x7fffu + ((ua >> 16) & 1u);
    ub += 0x7fffu + ((ub >> 16) & 1u);
    return (ua >> 16) | (ub & 0xffff0000u);
}

// edge_index may arrive as int64 (reference dtype) or int32 (harness-normalized).
__device__ __forceinline__ int edge_get(const void* ei, int is64, long long i) {
    return is64 ? (int)((const long long*)ei)[i] : ((const int*)ei)[i];
}

__global__ void k_detect(const unsigned int* __restrict__ e, int* flag) {
    unsigned int v = e[2 * threadIdx.x + 1];
    unsigned long long m = __ballot(v != 0u);
    if (threadIdx.x == 0) *flag = (m == 0ull) ? 1 : 0;
}

// ---- Pass 1: bin edges by dst>>7. Block-local LDS histogram -> one global
// reservation per (block,bin) -> scatter from LDS. Avoids same-address contention.
__global__ __launch_bounds__(256) void k_bin(const void* __restrict__ ei,
                                             const int* __restrict__ flag,
                                             int* __restrict__ bincnt,
                                             unsigned* __restrict__ staged,
                                             int* __restrict__ ovfcnt,
                                             unsigned* __restrict__ ovf) {
    __shared__ unsigned lpk[EPB];
    __shared__ int lhist[NBIN], lbase[NBIN], lcur[NBIN];
    int is64 = *flag;
    int t = threadIdx.x;
    long long e0 = (long long)blockIdx.x * EPB;
    for (int i = t; i < NBIN; i += 256) { lhist[i] = 0; lcur[i] = 0; }
    __syncthreads();
    for (int j = t; j < EPB; j += 256) {
        int s = edge_get(ei, is64, e0 + j);
        int d = edge_get(ei, is64, (long long)NE + e0 + j);
        unsigned p = ((unsigned)d << 16) | (unsigned)s;
        lpk[j] = p;
        atomicAdd(&lhist[d >> 7], 1);
    }
    __syncthreads();
    for (int i = t; i < NBIN; i += 256)
        lbase[i] = (lhist[i] > 0) ? atomicAdd(&bincnt[i], lhist[i]) : 0;
    __syncthreads();
    for (int j = t; j < EPB; j += 256) {
        unsigned p = lpk[j];
        int bin = p >> 23;  // d>>7
        int pos = lbase[bin] + atomicAdd(&lcur[bin], 1);
        if (pos < STCAP) {
            staged[(long long)bin * STCAP + pos] = p;
        } else {
            int o = atomicAdd(ovfcnt, 1);
            if (o < OVFCAP) ovf[o] = p;
        }
    }
}

// ---- exclusive scan of bincnt -> binbase (csr index space); one block ----
__global__ __launch_bounds__(512) void k_binscan(const int* __restrict__ bincnt,
                                                 int* __restrict__ binbase) {
    __shared__ int s[512];
    int t = threadIdx.x;
    int v = (t < NBIN) ? bincnt[t] : 0;
    s[t] = v;
    __syncthreads();
#pragma unroll
    for (int off = 1; off < 512; off <<= 1) {
        int u = (t >= off) ? s[t - off] : 0;
        __syncthreads();
        s[t] += u;
        __syncthreads();
    }
    if (t < NBIN) binbase[t] = s[t] - v;
}

// ---- Pass 2: per bin, LDS count + scan; write rowstart/cnt/dinv; scatter csr ----
__global__ __launch_bounds__(256) void k_csr(const unsigned* __restrict__ staged,
                                             const int* __restrict__ bincnt,
                                             const int* __restrict__ binbase,
                                             const int* __restrict__ ovfcnt,
                                             const unsigned* __restrict__ ovf,
                                             int* __restrict__ rowstart,
                                             int* __restrict__ cnt,
                                             float* __restrict__ dinv,
                                             int* __restrict__ csr) {
    __shared__ int lcnt[BINW], lpre[BINW], lcur[BINW];
    int b = blockIdx.x, t = threadIdx.x;
    int n = min(bincnt[b], STCAP);
    int novf = *ovfcnt;  // statistically 0
    const unsigned* st = staged + (long long)b * STCAP;
    if (t < BINW) { lcnt[t] = 0; lcur[t] = 0; }
    __syncthreads();
    for (int j = t; j < n; j += 256) atomicAdd(&lcnt[(st[j] >> 16) & (BINW - 1)], 1);
    for (int j = t; j < novf; j += 256) {
        unsigned p = ovf[j];
        if ((int)(p >> 23) == b) atomicAdd(&lcnt[(p >> 16) & (BINW - 1)], 1);
    }
    __syncthreads();
    if (t < BINW) lpre[t] = lcnt[t];
    __syncthreads();
#pragma unroll
    for (int off = 1; off < BINW; off <<= 1) {
        int u = (t < BINW && t >= off) ? lpre[t - off] : 0;
        __syncthreads();
        if (t < BINW && t >= off) lpre[t] += u;
        __syncthreads();
    }
    int base = binbase[b];
    if (t < BINW) {
        int c = lcnt[t];
        int ex = lpre[t] - c;  // exclusive prefix
        lpre[t] = ex;
        int node = b * BINW + t;
        if (node < NN) {
            rowstart[node] = base + ex;
            cnt[node] = c;
            dinv[node] = rsqrtf((float)c + 1.0f);
        }
    }
    __syncthreads();
    for (int j = t; j < n; j += 256) {
        unsigned p = st[j];
        int dloc = (p >> 16) & (BINW - 1);
        int pos = base + lpre[dloc] + atomicAdd(&lcur[dloc], 1);
        csr[pos] = (int)(p & 0xffffu);
    }
    for (int j = t; j < novf; j += 256) {
        unsigned p = ovf[j];
        if ((int)(p >> 23) == b) {
            int dloc = (p >> 16) & (BINW - 1);
            int pos = base + lpre[dloc] + atomicAdd(&lcur[dloc], 1);
            csr[pos] = (int)(p & 0xffffu);
        }
    }
}

// ---- GEMM with dinv-row-scale epilogue, bf16 output.
// BM=64 rows, full CN cols, 256 threads (16x16), per-thread 4 rows x (CN/64 groups of 4 cols).
template <int K, int CN, bool XBF>
__global__ __launch_bounds__(256) void k_gemm_scale(const void* __restrict__ Xv,
                                                    const float* __restrict__ W,
                                                    const float* __restrict__ dinv,
                                                    unsigned int* __restrict__ outb) {
    const int BM = 64, KT = 16, G = CN / 64;
    __shared__ float As[KT][BM + 4];
    __shared__ float Bs[KT][CN];
    int tid = threadIdx.x;
    int tx = tid & 15, ty = tid >> 4;
    int row0 = blockIdx.x * BM;
    float acc[4][G * 4];
#pragma unroll
    for (int a = 0; a < 4; a++)
#pragma unroll
        for (int b = 0; b < G * 4; b++) acc[a][b] = 0.f;

    for (int k0 = 0; k0 < K; k0 += KT) {
        if (XBF) {
            if (tid < 128) {
                int r = tid >> 1, kc = tid & 1, rr = row0 + r;
                uint4 v = {0, 0, 0, 0};
                if (rr < NN)
                    v = ((const uint4*)Xv)[((long long)rr * K + k0 + 8 * kc) >> 3];
                int kb = 8 * kc;
                As[kb + 0][r] = blo(v.x); As[kb + 1][r] = bhi(v.x);
                As[kb + 2][r] = blo(v.y); As[kb + 3][r] = bhi(v.y);
                As[kb + 4][r] = blo(v.z); As[kb + 5][r] = bhi(v.z);
                As[kb + 6][r] = blo(v.w); As[kb + 7][r] = bhi(v.w);
            }
        } else {
            int r = tid >> 2, kc = tid & 3, rr = row0 + r;
            float4 v = {0.f, 0.f, 0.f, 0.f};
            if (rr < NN)
                v = *(const float4*)((const float*)Xv + (long long)rr * K + k0 + 4 * kc);
            int kb = 4 * kc;
            As[kb + 0][r] = v.x; As[kb + 1][r] = v.y;
            As[kb + 2][r] = v.z; As[kb + 3][r] = v.w;
        }
#pragma unroll
        for (int j = 0; j < (KT * CN / 4) / 256; j++) {
            int q = tid + 256 * j;
            int kk = q / (CN / 4), c4 = q % (CN / 4);
            *(float4*)&Bs[kk][4 * c4] = *(const float4*)&W[(long long)(k0 + kk) * CN + 4 * c4];
        }
        __syncthreads();
#pragma unroll
        for (int kk = 0; kk < KT; kk++) {
            float4 av = *(const float4*)&As[kk][ty * 4];
            float am[4] = {av.x, av.y, av.z, av.w};
            float bm[G][4];
#pragma unroll
            for (int g = 0; g < G; g++) {
                float4 bv = *(const float4*)&Bs[kk][g * 64 + tx * 4];
                bm[g][0] = bv.x; bm[g][1] = bv.y; bm[g][2] = bv.z; bm[g][3] = bv.w;
            }
#pragma unroll
            for (int mi = 0; mi < 4; mi++)
#pragma unroll
                for (int g = 0; g < G; g++)
#pragma unroll
                    for (int ni = 0; ni < 4; ni++)
                        acc[mi][g * 4 + ni] = fmaf(am[mi], bm[g][ni], acc[mi][g * 4 + ni]);
        }
        __syncthreads();
    }
#pragma unroll
    for (int mi = 0; mi < 4; mi++) {
        int r = row0 + ty * 4 + mi;
        if (r < NN) {
            float s = dinv[r];
#pragma unroll
            for (int g = 0; g < G; g++) {
                uint2 u;
                u.x = bpack(s * acc[mi][g * 4 + 0], s * acc[mi][g * 4 + 1]);
                u.y = bpack(s * acc[mi][g * 4 + 2], s * acc[mi][g * 4 + 3]);
                long long elem = (long long)r * CN + g * 64 + tx * 4;
                *(uint2*)(outb + (elem >> 1)) = u;
            }
        }
    }
}

// ---- Layer-1 aggregate: out1 = relu(dinv*(self + sum_in h1) + b). bf16 in/out.
// 16 lanes/node (8 ch each), 16 nodes/block.
__global__ __launch_bounds__(256) void k_gather_relu(const uint4* __restrict__ h,
                                                     const int* __restrict__ csr,
                                                     const int* __restrict__ rowstart,
                                                     const int* __restrict__ cnt,
                                                     const float* __restrict__ dinv,
                                                     const float* __restrict__ bias,
                                                     uint4* __restrict__ out) {
    int tid = threadIdx.x;
    int node = blockIdx.x * 16 + (tid >> 4);
    int cl = tid & 15;
    if (node >= NN) return;
    int beg = rowstart[node], n = cnt[node];
    float acc[8];
    {
        uint4 v = h[(long long)node * 16 + cl];
        acc[0] = blo(v.x); acc[1] = bhi(v.x); acc[2] = blo(v.y); acc[3] = bhi(v.y);
        acc[4] = blo(v.z); acc[5] = bhi(v.z); acc[6] = blo(v.w); acc[7] = bhi(v.w);
    }
    int j = 0;
    for (; j + 3 < n; j += 4) {
        int a0 = csr[beg + j], a1 = csr[beg + j + 1];
        int a2 = csr[beg + j + 2], a3 = csr[beg + j + 3];
        uint4 v0 = h[(long long)a0 * 16 + cl], v1 = h[(long long)a1 * 16 + cl];
        uint4 v2 = h[(long long)a2 * 16 + cl], v3 = h[(long long)a3 * 16 + cl];
        acc[0] += blo(v0.x); acc[1] += bhi(v0.x); acc[2] += blo(v0.y); acc[3] += bhi(v0.y);
        acc[4] += blo(v0.z); acc[5] += bhi(v0.z); acc[6] += blo(v0.w); acc[7] += bhi(v0.w);
        acc[0] += blo(v1.x); acc[1] += bhi(v1.x); acc[2] += blo(v1.y); acc[3] += bhi(v1.y);
        acc[4] += blo(v1.z); acc[5] += bhi(v1.z); acc[6] += blo(v1.w); acc[7] += bhi(v1.w);
        acc[0] += blo(v2.x); acc[1] += bhi(v2.x); acc[2] += blo(v2.y); acc[3] += bhi(v2.y);
        acc[4] += blo(v2.z); acc[5] += bhi(v2.z); acc[6] += blo(v2.w); acc[7] += bhi(v2.w);
        acc[0] += blo(v3.x); acc[1] += bhi(v3.x); acc[2] += blo(v3.y); acc[3] += bhi(v3.y);
        acc[4] += blo(v3.z); acc[5] += bhi(v3.z); acc[6] += blo(v3.w); acc[7] += bhi(v3.w);
    }
    for (; j < n; j++) {
        uint4 v = h[(long long)csr[beg + j] * 16 + cl];
        acc[0] += blo(v.x); acc[1] += bhi(v.x); acc[2] += blo(v.y); acc[3] += bhi(v.y);
        acc[4] += blo(v.z); acc[5] += bhi(v.z); acc[6] += blo(v.w); acc[7] += bhi(v.w);
    }
    float d = dinv[node];
    float4 b0 = *(const float4*)&bias[cl * 8];
    float4 b1 = *(const float4*)&bias[cl * 8 + 4];
    float r0 = fmaxf(fmaf(d, acc[0], b0.x), 0.f), r1 = fmaxf(fmaf(d, acc[1], b0.y), 0.f);
    float r2 = fmaxf(fmaf(d, acc[2], b0.z), 0.f), r3 = fmaxf(fmaf(d, acc[3], b0.w), 0.f);
    float r4 = fmaxf(fmaf(d, acc[4], b1.x), 0.f), r5 = fmaxf(fmaf(d, acc[5], b1.y), 0.f);
    float r6 = fmaxf(fmaf(d, acc[6], b1.z), 0.f), r7 = fmaxf(fmaf(d, acc[7], b1.w), 0.f);
    uint4 o;
    o.x = bpack(r0, r1); o.y = bpack(r2, r3); o.z = bpack(r4, r5); o.w = bpack(r6, r7);
    out[(long long)node * 16 + cl] = o;
}

// ---- Layer-2 aggregate + bias + log_softmax. bf16 in, f32 out.
// 8 lanes/node (8 ch each), 32 nodes/block; shfl_xor reduce within 8-lane group.
__global__ __launch_bounds__(256) void k_gather_lsm(const uint4* __restrict__ h,
                                                    const int* __restrict__ csr,
                                                    const int* __restrict__ rowstart,
                                                    const int* __restrict__ cnt,
                                                    const float* __restrict__ dinv,
                                                    const float* __restrict__ bias,
                                                    float* __restrict__ out) {
    int tid = threadIdx.x;
    int node = blockIdx.x * 32 + (tid >> 3);
    int cl = tid & 7;
    if (node >= NN) return;
    int beg = rowstart[node], n = cnt[node];
    float acc[8];
    {
        uint4 v = h[(long long)node * 8 + cl];
        acc[0] = blo(v.x); acc[1] = bhi(v.x); acc[2] = blo(v.y); acc[3] = bhi(v.y);
        acc[4] = blo(v.z); acc[5] = bhi(v.z); acc[6] = blo(v.w); acc[7] = bhi(v.w);
    }
    int j = 0;
    for (; j + 3 < n; j += 4) {
        int a0 = csr[beg + j], a1 = csr[beg + j + 1];
        int a2 = csr[beg + j + 2], a3 = csr[beg + j + 3];
        uint4 v0 = h[(long long)a0 * 8 + cl], v1 = h[(long long)a1 * 8 + cl];
        uint4 v2 = h[(long long)a2 * 8 + cl], v3 = h[(long long)a3 * 8 + cl];
        acc[0] += blo(v0.x); acc[1] += bhi(v0.x); acc[2] += blo(v0.y); acc[3] += bhi(v0.y);
        acc[4] += blo(v0.z); acc[5] += bhi(v0.z); acc[6] += blo(v0.w); acc[7] += bhi(v0.w);
        acc[0] += blo(v1.x); acc[1] += bhi(v1.x); acc[2] += blo(v1.y); acc[3] += bhi(v1.y);
        acc[4] += blo(v1.z); acc[5] += bhi(v1.z); acc[6] += blo(v1.w); acc[7] += bhi(v1.w);
        acc[0] += blo(v2.x); acc[1] += bhi(v2.x); acc[2] += blo(v2.y); acc[3] += bhi(v2.y);
        acc[4] += blo(v2.z); acc[5] += bhi(v2.z); acc[6] += blo(v2.w); acc[7] += bhi(v2.w);
        acc[0] += blo(v3.x); acc[1] += bhi(v3.x); acc[2] += blo(v3.y); acc[3] += bhi(v3.y);
        acc[4] += blo(v3.z); acc[5] += bhi(v3.z); acc[6] += blo(v3.w); acc[7] += bhi(v3.w);
    }
    for (; j < n; j++) {
        uint4 v = h[(long long)csr[beg + j] * 8 + cl];
        acc[0] += blo(v.x); acc[1] += bhi(v.x); acc[2] += blo(v.y); acc[3] += bhi(v.y);
        acc[4] += blo(v.z); acc[5] += bhi(v.z); acc[6] += blo(v.w); acc[7] += bhi(v.w);
    }
    float d = dinv[node];
    float4 b0 = *(const float4*)&bias[cl * 8];
    float4 b1 = *(const float4*)&bias[cl * 8 + 4];
    float t[8];
    t[0] = fmaf(d, acc[0], b0.x); t[1] = fmaf(d, acc[1], b0.y);
    t[2] = fmaf(d, acc[2], b0.z); t[3] = fmaf(d, acc[3], b0.w);
    t[4] = fmaf(d, acc[4], b1.x); t[5] = fmaf(d, acc[5], b1.y);
    t[6] = fmaf(d, acc[6], b1.z); t[7] = fmaf(d, acc[7], b1.w);
    float m = t[0];
#pragma unroll
    for (int i = 1; i < 8; i++) m = fmaxf(m, t[i]);
#pragma unroll
    for (int o = 1; o < 8; o <<= 1) m = fmaxf(m, __shfl_xor(m, o));
    float ex = 0.f;
#pragma unroll
    for (int i = 0; i < 8; i++) ex += __expf(t[i] - m);
#pragma unroll
    for (int o = 1; o < 8; o <<= 1) ex += __shfl_xor(ex, o);
    float l = logf(ex);
    float4 w0 = {t[0] - m - l, t[1] - m - l, t[2] - m - l, t[3] - m - l};
    float4 w1 = {t[4] - m - l, t[5] - m - l, t[6] - m - l, t[7] - m - l};
    *(float4*)&out[(long long)node * 64 + cl * 8] = w0;
    *(float4*)&out[(long long)node * 64 + cl * 8 + 4] = w1;
}

extern "C" void kernel_launch(void* const* d_in, const int* in_sizes, int n_in,
                              void* d_out, int out_size, void* d_ws, size_t ws_size,
                              hipStream_t stream) {
    const float* x  = (const float*)d_in[0];
    const void*  ei = d_in[1];
    const float* W1 = (const float*)d_in[2];
    const float* b1 = (const float*)d_in[3];
    const float* W2 = (const float*)d_in[4];
    const float* b2 = (const float*)d_in[5];
    float* out = (float*)d_out;

    char* ws = (char*)d_ws;
    float*    dinv     = (float*)   (ws + 0x000000);  // 200 KB
    int*      flag     = (int*)     (ws + 0x040000);
    int*      cnt      = (int*)     (ws + 0x050000);  // 200 KB
    int*      rowstart = (int*)     (ws + 0x090000);  // 200 KB
    int*      bincnt   = (int*)     (ws + 0x0D0000);  // NBIN ints (+ ovfcnt right after)
    int*      ovfcnt   = (int*)     (ws + 0x0D0000 + NBIN * 4);
    int*      binbase  = (int*)     (ws + 0x0D2000);  // NBIN ints
    unsigned* ovf      = (unsigned*)(ws + 0x0E0000);  // 128 KB
    int*      csr      = (int*)     (ws + 0x120000);  // 6.4 MB
    unsigned* h1       = (unsigned*)(ws + 0x740000);  // bf16 12.8 MB (h1, then h2)
    unsigned* out1     = (unsigned*)(ws + 0x1400000); // bf16 12.8 MB
    unsigned* staged   = (unsigned*)(ws + 0x1400000); // 9.6 MB, aliases out1 (dead before gemm1)

    k_detect<<<1, 64, 0, stream>>>((const unsigned int*)ei, flag);
    hipMemsetAsync(bincnt, 0, (size_t)(NBIN + 1) * 4, stream);  // bincnt + ovfcnt
    k_bin<<<NBLK, 256, 0, stream>>>(ei, flag, bincnt, staged, ovfcnt, ovf);
    k_binscan<<<1, 512, 0, stream>>>(bincnt, binbase);
    k_csr<<<NBIN, 256, 0, stream>>>(staged, bincnt, binbase, ovfcnt, ovf,
                                    rowstart, cnt, dinv, csr);

    // Layer 1: h1 = bf16(dinv .* (x@W1)); out1 = bf16(relu(dinv.*(agg+self) + b1))
    k_gemm_scale<256, 128, false><<<(NN + 63) / 64, 256, 0, stream>>>(x, W1, dinv, h1);
    k_gather_relu<<<(NN + 15) / 16, 256, 0, stream>>>((const uint4*)h1, csr, rowstart, cnt,
                                                      dinv, b1, (uint4*)out1);

    // Layer 2: h2 = bf16(dinv .* (out1@W2)); out = log_softmax(dinv.*(agg+self) + b2)
    k_gemm_scale<128, 64, true><<<(NN + 63) / 64, 256, 0, stream>>>(out1, W2, dinv, h1);
    k_gather_lsm<<<(NN + 31) / 32, 256, 0, stream>>>((const uint4*)h1, csr, rowstart, cnt,
                                                     dinv, b2, out);
}

// Round 10
// 247.612 us; speedup vs baseline: 3.3424x; 1.1847x over previous
//
#include <hip/hip_runtime.h>
#include <math.h>

#define NN 50000
#define NE 1600000
#define NBIN 391    // ceil(NN/128)
#define BINW 128    // nodes per bin
#define STCAP 6144  // staged edges per bin (mean 4092)
#define OVFCAP 32768
#define NBLK 512
#define EPB 3125    // NE / NBLK exactly

typedef __attribute__((ext_vector_type(8))) short bf16x8;
typedef __attribute__((ext_vector_type(4))) float f32x4;
union frag_u { unsigned u[4]; bf16x8 v; };

// ---- bf16 helpers (bit-level, RNE pack) ----
__device__ __forceinline__ float blo(unsigned u) { return __uint_as_float(u << 16); }
__device__ __forceinline__ float bhi(unsigned u) { return __uint_as_float(u & 0xffff0000u); }
__device__ __forceinline__ unsigned bpack(float a, float b) {
    unsigned ua = __float_as_uint(a), ub = __float_as_uint(b);
    ua += 0x7fffu + ((ua >> 16) & 1u);
    ub += 0x7fffu + ((ub >> 16) & 1u);
    return (ua >> 16) | (ub & 0xffff0000u);
}
__device__ __forceinline__ unsigned short b16(float a) {
    unsigned ua = __float_as_uint(a);
    ua += 0x7fffu + ((ua >> 16) & 1u);
    return (unsigned short)(ua >> 16);
}

// edge_index may arrive as int64 (reference dtype) or int32 (harness-normalized).
__device__ __forceinline__ int edge_get(const void* ei, int is64, long long i) {
    return is64 ? (int)((const long long*)ei)[i] : ((const int*)ei)[i];
}

__global__ void k_detect(const unsigned int* __restrict__ e, int* flag) {
    unsigned int v = e[2 * threadIdx.x + 1];
    unsigned long long m = __ballot(v != 0u);
    if (threadIdx.x == 0) *flag = (m == 0ull) ? 1 : 0;
}

// ---- Pass 1: bin edges by dst>>7. Block-local LDS histogram -> one global
// reservation per (block,bin) -> scatter from LDS. Avoids same-address contention.
__global__ __launch_bounds__(256) void k_bin(const void* __restrict__ ei,
                                             const int* __restrict__ flag,
                                             int* __restrict__ bincnt,
                                             unsigned* __restrict__ staged,
                                             int* __restrict__ ovfcnt,
                                             unsigned* __restrict__ ovf) {
    __shared__ unsigned lpk[EPB];
    __shared__ int lhist[NBIN], lbase[NBIN], lcur[NBIN];
    int is64 = *flag;
    int t = threadIdx.x;
    long long e0 = (long long)blockIdx.x * EPB;
    for (int i = t; i < NBIN; i += 256) { lhist[i] = 0; lcur[i] = 0; }
    __syncthreads();
    for (int j = t; j < EPB; j += 256) {
        int s = edge_get(ei, is64, e0 + j);
        int d = edge_get(ei, is64, (long long)NE + e0 + j);
        unsigned p = ((unsigned)d << 16) | (unsigned)s;
        lpk[j] = p;
        atomicAdd(&lhist[d >> 7], 1);
    }
    __syncthreads();
    for (int i = t; i < NBIN; i += 256)
        lbase[i] = (lhist[i] > 0) ? atomicAdd(&bincnt[i], lhist[i]) : 0;
    __syncthreads();
    for (int j = t; j < EPB; j += 256) {
        unsigned p = lpk[j];
        int bin = p >> 23;  // d>>7
        int pos = lbase[bin] + atomicAdd(&lcur[bin], 1);
        if (pos < STCAP) {
            staged[(long long)bin * STCAP + pos] = p;
        } else {
            int o = atomicAdd(ovfcnt, 1);
            if (o < OVFCAP) ovf[o] = p;
        }
    }
}

// ---- exclusive scan of bincnt -> binbase (csr index space); one block ----
__global__ __launch_bounds__(512) void k_binscan(const int* __restrict__ bincnt,
                                                 int* __restrict__ binbase) {
    __shared__ int s[512];
    int t = threadIdx.x;
    int v = (t < NBIN) ? bincnt[t] : 0;
    s[t] = v;
    __syncthreads();
#pragma unroll
    for (int off = 1; off < 512; off <<= 1) {
        int u = (t >= off) ? s[t - off] : 0;
        __syncthreads();
        s[t] += u;
        __syncthreads();
    }
    if (t < NBIN) binbase[t] = s[t] - v;
}

// ---- Pass 2: per bin, LDS count + scan; write rowstart/cnt/dinv; scatter csr ----
__global__ __launch_bounds__(256) void k_csr(const unsigned* __restrict__ staged,
                                             const int* __restrict__ bincnt,
                                             const int* __restrict__ binbase,
                                             const int* __restrict__ ovfcnt,
                                             const unsigned* __restrict__ ovf,
                                             int* __restrict__ rowstart,
                                             int* __restrict__ cnt,
                                             float* __restrict__ dinv,
                                             int* __restrict__ csr) {
    __shared__ int lcnt[BINW], lpre[BINW], lcur[BINW];
    int b = blockIdx.x, t = threadIdx.x;
    int n = min(bincnt[b], STCAP);
    int novf = *ovfcnt;  // statistically 0
    const unsigned* st = staged + (long long)b * STCAP;
    if (t < BINW) { lcnt[t] = 0; lcur[t] = 0; }
    __syncthreads();
    for (int j = t; j < n; j += 256) atomicAdd(&lcnt[(st[j] >> 16) & (BINW - 1)], 1);
    for (int j = t; j < novf; j += 256) {
        unsigned p = ovf[j];
        if ((int)(p >> 23) == b) atomicAdd(&lcnt[(p >> 16) & (BINW - 1)], 1);
    }
    __syncthreads();
    if (t < BINW) lpre[t] = lcnt[t];
    __syncthreads();
#pragma unroll
    for (int off = 1; off < BINW; off <<= 1) {
        int u = (t < BINW && t >= off) ? lpre[t - off] : 0;
        __syncthreads();
        if (t < BINW && t >= off) lpre[t] += u;
        __syncthreads();
    }
    int base = binbase[b];
    if (t < BINW) {
        int c = lcnt[t];
        int ex = lpre[t] - c;  // exclusive prefix
        lpre[t] = ex;
        int node = b * BINW + t;
        if (node < NN) {
            rowstart[node] = base + ex;
            cnt[node] = c;
            dinv[node] = rsqrtf((float)c + 1.0f);
        }
    }
    __syncthreads();
    for (int j = t; j < n; j += 256) {
        unsigned p = st[j];
        int dloc = (p >> 16) & (BINW - 1);
        int pos = base + lpre[dloc] + atomicAdd(&lcur[dloc], 1);
        csr[pos] = (int)(p & 0xffffu);
    }
    for (int j = t; j < novf; j += 256) {
        unsigned p = ovf[j];
        if ((int)(p >> 23) == b) {
            int dloc = (p >> 16) & (BINW - 1);
            int pos = base + lpre[dloc] + atomicAdd(&lcur[dloc], 1);
            csr[pos] = (int)(p & 0xffffu);
        }
    }
}

// ---- Layer-1 GEMM via MFMA: h1[r][c] = bf16(dinv[r] * (x@W1)[r][c]).
// 4 waves, BM=64 rows; each wave 16 rows x 128 cols (8 frags), K=256 in 8 steps.
// A-frags straight from global f32 (lane row=l&15, kgroup=(l>>4)*8). W1 -> LDS bf16
// transposed [col][k] with +8 pad: stride 528B = 4 words mod 32 -> 2-way (free).
__global__ __launch_bounds__(256) void k_mm1(const float* __restrict__ X,
                                             const float* __restrict__ W,
                                             const float* __restrict__ dinv,
                                             unsigned short* __restrict__ outh) {
    __shared__ unsigned short Wt[128][264];
    int tid = threadIdx.x;
    for (int idx = tid; idx < 128 * 256; idx += 256) {
        int col = idx & 127, k = idx >> 7;
        Wt[col][k] = b16(W[k * 128 + col]);
    }
    __syncthreads();
    int w = tid >> 6, l = tid & 63;
    int lr = l & 15, kg = l >> 4;
    int row = blockIdx.x * 64 + w * 16 + lr;
    long long rowc = min(row, NN - 1);
    f32x4 acc[8];
#pragma unroll
    for (int cf = 0; cf < 8; cf++) acc[cf] = {0.f, 0.f, 0.f, 0.f};
#pragma unroll
    for (int ks = 0; ks < 8; ks++) {
        int k0 = ks * 32 + kg * 8;
        const float4* p = (const float4*)(X + rowc * 256 + k0);
        float4 v0 = p[0], v1 = p[1];
        frag_u a;
        a.u[0] = bpack(v0.x, v0.y); a.u[1] = bpack(v0.z, v0.w);
        a.u[2] = bpack(v1.x, v1.y); a.u[3] = bpack(v1.z, v1.w);
#pragma unroll
        for (int cf = 0; cf < 8; cf++) {
            uint4 bb = *(const uint4*)&Wt[cf * 16 + lr][k0];
            frag_u b;
            b.u[0] = bb.x; b.u[1] = bb.y; b.u[2] = bb.z; b.u[3] = bb.w;
            acc[cf] = __builtin_amdgcn_mfma_f32_16x16x32_bf16(a.v, b.v, acc[cf], 0, 0, 0);
        }
    }
    int orow0 = blockIdx.x * 64 + w * 16 + kg * 4;
#pragma unroll
    for (int r = 0; r < 4; r++) {
        int orow = orow0 + r;
        if (orow < NN) {
            float s = dinv[orow];
#pragma unroll
            for (int cf = 0; cf < 8; cf++)
                outh[(long long)orow * 128 + cf * 16 + lr] = b16(s * acc[cf][r]);
        }
    }
}

// ---- Layer-2 GEMM via MFMA: h2[r][c] = bf16(dinv[r] * (out1@W2)[r][c]).
// out1 is bf16 [NN][128]; W2 f32 [128][64]. Each wave 16 rows x 64 cols, K=128 in 4 steps.
__global__ __launch_bounds__(256) void k_mm2(const unsigned short* __restrict__ Xh,
                                             const float* __restrict__ W,
                                             const float* __restrict__ dinv,
                                             unsigned short* __restrict__ outh) {
    __shared__ unsigned short Wt[64][136];
    int tid = threadIdx.x;
    for (int idx = tid; idx < 64 * 128; idx += 256) {
        int col = idx & 63, k = idx >> 6;
        Wt[col][k] = b16(W[k * 64 + col]);
    }
    __syncthreads();
    int w = tid >> 6, l = tid & 63;
    int lr = l & 15, kg = l >> 4;
    int row = blockIdx.x * 64 + w * 16 + lr;
    long long rowc = min(row, NN - 1);
    f32x4 acc[4];
#pragma unroll
    for (int cf = 0; cf < 4; cf++) acc[cf] = {0.f, 0.f, 0.f, 0.f};
#pragma unroll
    for (int ks = 0; ks < 4; ks++) {
        int k0 = ks * 32 + kg * 8;
        uint4 av = *(const uint4*)(Xh + rowc * 128 + k0);
        frag_u a;
        a.u[0] = av.x; a.u[1] = av.y; a.u[2] = av.z; a.u[3] = av.w;
#pragma unroll
        for (int cf = 0; cf < 4; cf++) {
            uint4 bb = *(const uint4*)&Wt[cf * 16 + lr][k0];
            frag_u b;
            b.u[0] = bb.x; b.u[1] = bb.y; b.u[2] = bb.z; b.u[3] = bb.w;
            acc[cf] = __builtin_amdgcn_mfma_f32_16x16x32_bf16(a.v, b.v, acc[cf], 0, 0, 0);
        }
    }
    int orow0 = blockIdx.x * 64 + w * 16 + kg * 4;
#pragma unroll
    for (int r = 0; r < 4; r++) {
        int orow = orow0 + r;
        if (orow < NN) {
            float s = dinv[orow];
#pragma unroll
            for (int cf = 0; cf < 4; cf++)
                outh[(long long)orow * 64 + cf * 16 + lr] = b16(s * acc[cf][r]);
        }
    }
}

// ---- Layer-1 aggregate: out1 = relu(dinv*(self + sum_in h1) + b). bf16 in/out.
// 16 lanes/node (8 ch each), 16 nodes/block.
__global__ __launch_bounds__(256) void k_gather_relu(const uint4* __restrict__ h,
                                                     const int* __restrict__ csr,
                                                     const int* __restrict__ rowstart,
                                                     const int* __restrict__ cnt,
                                                     const float* __restrict__ dinv,
                                                     const float* __restrict__ bias,
                                                     uint4* __restrict__ out) {
    int tid = threadIdx.x;
    int node = blockIdx.x * 16 + (tid >> 4);
    int cl = tid & 15;
    if (node >= NN) return;
    int beg = rowstart[node], n = cnt[node];
    float acc[8];
    {
        uint4 v = h[(long long)node * 16 + cl];
        acc[0] = blo(v.x); acc[1] = bhi(v.x); acc[2] = blo(v.y); acc[3] = bhi(v.y);
        acc[4] = blo(v.z); acc[5] = bhi(v.z); acc[6] = blo(v.w); acc[7] = bhi(v.w);
    }
    int j = 0;
    for (; j + 3 < n; j += 4) {
        int a0 = csr[beg + j], a1 = csr[beg + j + 1];
        int a2 = csr[beg + j + 2], a3 = csr[beg + j + 3];
        uint4 v0 = h[(long long)a0 * 16 + cl], v1 = h[(long long)a1 * 16 + cl];
        uint4 v2 = h[(long long)a2 * 16 + cl], v3 = h[(long long)a3 * 16 + cl];
        acc[0] += blo(v0.x); acc[1] += bhi(v0.x); acc[2] += blo(v0.y); acc[3] += bhi(v0.y);
        acc[4] += blo(v0.z); acc[5] += bhi(v0.z); acc[6] += blo(v0.w); acc[7] += bhi(v0.w);
        acc[0] += blo(v1.x); acc[1] += bhi(v1.x); acc[2] += blo(v1.y); acc[3] += bhi(v1.y);
        acc[4] += blo(v1.z); acc[5] += bhi(v1.z); acc[6] += blo(v1.w); acc[7] += bhi(v1.w);
        acc[0] += blo(v2.x); acc[1] += bhi(v2.x); acc[2] += blo(v2.y); acc[3] += bhi(v2.y);
        acc[4] += blo(v2.z); acc[5] += bhi(v2.z); acc[6] += blo(v2.w); acc[7] += bhi(v2.w);
        acc[0] += blo(v3.x); acc[1] += bhi(v3.x); acc[2] += blo(v3.y); acc[3] += bhi(v3.y);
        acc[4] += blo(v3.z); acc[5] += bhi(v3.z); acc[6] += blo(v3.w); acc[7] += bhi(v3.w);
    }
    for (; j < n; j++) {
        uint4 v = h[(long long)csr[beg + j] * 16 + cl];
        acc[0] += blo(v.x); acc[1] += bhi(v.x); acc[2] += blo(v.y); acc[3] += bhi(v.y);
        acc[4] += blo(v.z); acc[5] += bhi(v.z); acc[6] += blo(v.w); acc[7] += bhi(v.w);
    }
    float d = dinv[node];
    float4 b0 = *(const float4*)&bias[cl * 8];
    float4 b1 = *(const float4*)&bias[cl * 8 + 4];
    float r0 = fmaxf(fmaf(d, acc[0], b0.x), 0.f), r1 = fmaxf(fmaf(d, acc[1], b0.y), 0.f);
    float r2 = fmaxf(fmaf(d, acc[2], b0.z), 0.f), r3 = fmaxf(fmaf(d, acc[3], b0.w), 0.f);
    float r4 = fmaxf(fmaf(d, acc[4], b1.x), 0.f), r5 = fmaxf(fmaf(d, acc[5], b1.y), 0.f);
    float r6 = fmaxf(fmaf(d, acc[6], b1.z), 0.f), r7 = fmaxf(fmaf(d, acc[7], b1.w), 0.f);
    uint4 o;
    o.x = bpack(r0, r1); o.y = bpack(r2, r3); o.z = bpack(r4, r5); o.w = bpack(r6, r7);
    out[(long long)node * 16 + cl] = o;
}

// ---- Layer-2 aggregate + bias + log_softmax. bf16 in, f32 out.
// 8 lanes/node (8 ch each), 32 nodes/block; shfl_xor reduce within 8-lane group.
__global__ __launch_bounds__(256) void k_gather_lsm(const uint4* __restrict__ h,
                                                    const int* __restrict__ csr,
                                                    const int* __restrict__ rowstart,
                                                    const int* __restrict__ cnt,
                                                    const float* __restrict__ dinv,
                                                    const float* __restrict__ bias,
                                                    float* __restrict__ out) {
    int tid = threadIdx.x;
    int node = blockIdx.x * 32 + (tid >> 3);
    int cl = tid & 7;
    if (node >= NN) return;
    int beg = rowstart[node], n = cnt[node];
    float acc[8];
    {
        uint4 v = h[(long long)node * 8 + cl];
        acc[0] = blo(v.x); acc[1] = bhi(v.x); acc[2] = blo(v.y); acc[3] = bhi(v.y);
        acc[4] = blo(v.z); acc[5] = bhi(v.z); acc[6] = blo(v.w); acc[7] = bhi(v.w);
    }
    int j = 0;
    for (; j + 3 < n; j += 4) {
        int a0 = csr[beg + j], a1 = csr[beg + j + 1];
        int a2 = csr[beg + j + 2], a3 = csr[beg + j + 3];
        uint4 v0 = h[(long long)a0 * 8 + cl], v1 = h[(long long)a1 * 8 + cl];
        uint4 v2 = h[(long long)a2 * 8 + cl], v3 = h[(long long)a3 * 8 + cl];
        acc[0] += blo(v0.x); acc[1] += bhi(v0.x); acc[2] += blo(v0.y); acc[3] += bhi(v0.y);
        acc[4] += blo(v0.z); acc[5] += bhi(v0.z); acc[6] += blo(v0.w); acc[7] += bhi(v0.w);
        acc[0] += blo(v1.x); acc[1] += bhi(v1.x); acc[2] += blo(v1.y); acc[3] += bhi(v1.y);
        acc[4] += blo(v1.z); acc[5] += bhi(v1.z); acc[6] += blo(v1.w); acc[7] += bhi(v1.w);
        acc[0] += blo(v2.x); acc[1] += bhi(v2.x); acc[2] += blo(v2.y); acc[3] += bhi(v2.y);
        acc[4] += blo(v2.z); acc[5] += bhi(v2.z); acc[6] += blo(v2.w); acc[7] += bhi(v2.w);
        acc[0] += blo(v3.x); acc[1] += bhi(v3.x); acc[2] += blo(v3.y); acc[3] += bhi(v3.y);
        acc[4] += blo(v3.z); acc[5] += bhi(v3.z); acc[6] += blo(v3.w); acc[7] += bhi(v3.w);
    }
    for (; j < n; j++) {
        uint4 v = h[(long long)csr[beg + j] * 8 + cl];
        acc[0] += blo(v.x); acc[1] += bhi(v.x); acc[2] += blo(v.y); acc[3] += bhi(v.y);
        acc[4] += blo(v.z); acc[5] += bhi(v.z); acc[6] += blo(v.w); acc[7] += bhi(v.w);
    }
    float d = dinv[node];
    float4 b0 = *(const float4*)&bias[cl * 8];
    float4 b1 = *(const float4*)&bias[cl * 8 + 4];
    float t[8];
    t[0] = fmaf(d, acc[0], b0.x); t[1] = fmaf(d, acc[1], b0.y);
    t[2] = fmaf(d, acc[2], b0.z); t[3] = fmaf(d, acc[3], b0.w);
    t[4] = fmaf(d, acc[4], b1.x); t[5] = fmaf(d, acc[5], b1.y);
    t[6] = fmaf(d, acc[6], b1.z); t[7] = fmaf(d, acc[7], b1.w);
    float m = t[0];
#pragma unroll
    for (int i = 1; i < 8; i++) m = fmaxf(m, t[i]);
#pragma unroll
    for (int o = 1; o < 8; o <<= 1) m = fmaxf(m, __shfl_xor(m, o));
    float ex = 0.f;
#pragma unroll
    for (int i = 0; i < 8; i++) ex += __expf(t[i] - m);
#pragma unroll
    for (int o = 1; o < 8; o <<= 1) ex += __shfl_xor(ex, o);
    float l = logf(ex);
    float4 w0 = {t[0] - m - l, t[1] - m - l, t[2] - m - l, t[3] - m - l};
    float4 w1 = {t[4] - m - l, t[5] - m - l, t[6] - m - l, t[7] - m - l};
    *(float4*)&out[(long long)node * 64 + cl * 8] = w0;
    *(float4*)&out[(long long)node * 64 + cl * 8 + 4] = w1;
}

extern "C" void kernel_launch(void* const* d_in, const int* in_sizes, int n_in,
                              void* d_out, int out_size, void* d_ws, size_t ws_size,
                              hipStream_t stream) {
    const float* x  = (const float*)d_in[0];
    const void*  ei = d_in[1];
    const float* W1 = (const float*)d_in[2];
    const float* b1 = (const float*)d_in[3];
    const float* W2 = (const float*)d_in[4];
    const float* b2 = (const float*)d_in[5];
    float* out = (float*)d_out;

    char* ws = (char*)d_ws;
    float*          dinv     = (float*)   (ws + 0x000000);  // 200 KB
    int*            flag     = (int*)     (ws + 0x040000);
    int*            cnt      = (int*)     (ws + 0x050000);  // 200 KB
    int*            rowstart = (int*)     (ws + 0x090000);  // 200 KB
    int*            bincnt   = (int*)     (ws + 0x0D0000);  // NBIN ints (+ ovfcnt after)
    int*            ovfcnt   = (int*)     (ws + 0x0D0000 + NBIN * 4);
    int*            binbase  = (int*)     (ws + 0x0D2000);  // NBIN ints
    unsigned*       ovf      = (unsigned*)(ws + 0x0E0000);  // 128 KB
    int*            csr      = (int*)     (ws + 0x120000);  // 6.4 MB
    unsigned short* h1       = (unsigned short*)(ws + 0x740000);   // bf16 12.8 MB (h1, then h2)
    unsigned short* out1     = (unsigned short*)(ws + 0x1400000);  // bf16 12.8 MB
    unsigned*       staged   = (unsigned*)(ws + 0x1400000);  // 9.6 MB, aliases out1 (dead before mm1)

    k_detect<<<1, 64, 0, stream>>>((const unsigned int*)ei, flag);
    hipMemsetAsync(bincnt, 0, (size_t)(NBIN + 1) * 4, stream);  // bincnt + ovfcnt
    k_bin<<<NBLK, 256, 0, stream>>>(ei, flag, bincnt, staged, ovfcnt, ovf);
    k_binscan<<<1, 512, 0, stream>>>(bincnt, binbase);
    k_csr<<<NBIN, 256, 0, stream>>>(staged, bincnt, binbase, ovfcnt, ovf,
                                    rowstart, cnt, dinv, csr);

    // Layer 1: h1 = bf16(dinv .* (x@W1)); out1 = bf16(relu(dinv.*(agg+self) + b1))
    k_mm1<<<(NN + 63) / 64, 256, 0, stream>>>(x, W1, dinv, h1);
    k_gather_relu<<<(NN + 15) / 16, 256, 0, stream>>>((const uint4*)h1, csr, rowstart, cnt,
                                                      dinv, b1, (uint4*)out1);

    // Layer 2: h2 = bf16(dinv .* (out1@W2)); out = log_softmax(dinv.*(agg+self) + b2)
    k_mm2<<<(NN + 63) / 64, 256, 0, stream>>>(out1, W2, dinv, h1);
    k_gather_lsm<<<(NN + 31) / 32, 256, 0, stream>>>((const uint4*)h1, csr, rowstart, cnt,
                                                     dinv, b2, out);
}